// Round 10
// baseline (1064.568 us; speedup 1.0000x reference)
//
#include <hip/hip_runtime.h>
#include <math.h>
#include <stdint.h>

#define NANCH 76725
#define NPAD  131072
#define NPAD2 32768
#define PXTOT 8525

typedef _Float16 half8 __attribute__((ext_vector_type(8)));
typedef _Float16 half4 __attribute__((ext_vector_type(4)));
typedef float float4v __attribute__((ext_vector_type(4)));
typedef unsigned long long u64;

#define ACT2_EL  ((size_t)PXTOT * 512)     // [px][hi256|lo256] fp16
#define HEADC_EL (720 * PXTOT)
#define HEADR_EL (36 * PXTOT)

// prepped weight element counts (fp16): [tap9][split2][ciChunk8][co16][lane64][8]
#define TRUNK_WP_EL (9 * 2 * 8 * 16 * 64 * 8)    // NC16=16
#define CLSH_WP_EL  (9 * 2 * 8 * 48 * 64 * 8)    // NC16=48
#define REGH_WP_EL  (9 * 2 * 8 * 4 * 64 * 8)     // NC16=4

// ---------------------------------------------------------------- weight prep
// dst layout: B-fragment-native. frag(tap,s,cc,c16) = 1KB contiguous:
//   lane l: co = c16*16 + (l&15), ci = cc*32 + (l>>4)*8 + j  (j=0..7)
struct PrepArgs {
    const float* src[10];
    _Float16*    dst[10];
    int Co[10], NC16[10];
    long base[11];
};

__global__ __launch_bounds__(256) void prep_k(PrepArgs P)
{
    long idx = (long)blockIdx.x * 256 + threadIdx.x;
    if (idx >= P.base[10]) return;
    int e = 0;
    while (idx >= P.base[e + 1]) e++;
    long local = idx - P.base[e];
    const int NC16 = P.NC16[e], Co = P.Co[e];
    int lane = (int)(local & 63);
    long t2 = local >> 6;
    int c16 = (int)(t2 % NC16);
    long t3 = t2 / NC16;
    int cc = (int)(t3 & 7);
    int t4 = (int)(t3 >> 3);          // 0..17
    int s = t4 & 1, tap = t4 >> 1;
    int co = c16 * 16 + (lane & 15);
    int kb = cc * 32 + (lane >> 4) * 8;
    const float* src = P.src[e];
    half8 out;
#pragma unroll
    for (int j = 0; j < 8; j++) {
        float v = (co < Co) ? src[(size_t)(co * 256 + kb + j) * 9 + tap] : 0.f;
        _Float16 h = (_Float16)v;
        out[j] = s ? (_Float16)(v - (float)h) : h;
    }
    _Float16* dst = P.dst[e] + ((((size_t)(tap * 2 + s) * 8 + cc) * NC16 + c16) * 64 + lane) * 8;
    *(half8*)dst = out;
}

// ---------------------------------------------------------------- feats repack
// feats fp32 [256][HW] -> act2 [px][hi256|lo256] fp16
struct RepArgs { const float* src[5]; _Float16* dst; };

__global__ __launch_bounds__(256) void repack_k(RepArgs R)
{
    __shared__ float T[64][257];
    const int cumT[5] = {100, 125, 132, 134, 135};
    const int Wt[5]   = {80, 40, 20, 10, 5};
    const int pxB[5]  = {0, 6400, 8000, 8400, 8500};
    int t = blockIdx.x;
    int lv = 0; while (t >= cumT[lv]) lv++;
    int tile = t - (lv ? cumT[lv - 1] : 0);
    const int HW = Wt[lv] * Wt[lv];
    const int pxStart = tile * 64;
    const float* src = R.src[lv];
    const int tid = threadIdx.x, w = tid >> 6, l6 = tid & 63;
    int p = pxStart + l6;
    bool ok = p < HW;
    for (int ci = w; ci < 256; ci += 4)
        T[l6][ci] = ok ? src[(size_t)ci * HW + p] : 0.f;
    __syncthreads();
    _Float16* dst = R.dst + (size_t)pxB[lv] * 512;
    for (int px = w; px < 64; px += 4) {
        int pp = pxStart + px;
        if (pp >= HW) continue;
        half4 h, l;
#pragma unroll
        for (int j = 0; j < 4; j++) {
            float v = T[px][l6 * 4 + j];
            _Float16 hh = (_Float16)v;
            h[j] = hh; l[j] = (_Float16)(v - (float)hh);
        }
        *(half4*)(dst + (size_t)pp * 512 + l6 * 4) = h;
        *(half4*)(dst + (size_t)pp * 512 + 256 + l6 * 4) = l;
    }
}

// ---------------------------------------------------------------- conv
// 4-wave blocks: 8x4 px tile, shared 6x10 halo in LDS; wave w -> 32 co.
// Pipelined: act staging for chunk cc+1 prefetched into regs during chunk cc;
// B-frags double-buffered across taps; LDS slot XOR-swizzled by (quad+lpx)&3
// to break the 4-bank-group aliasing (was 13.6M conflict cycles).
struct C3Args {
    const _Float16* aIn0; const _Float16* aIn1;
    _Float16* aOut0; _Float16* aOut1;     // trunk (mode=0)
    float* hOut0; float* hOut1;           // head (mode=1), layout [co][px]
    const _Float16* wp0; const _Float16* wp1;
    const float* bias0; const float* bias1;
    int CoPad0, CoPad1, Co0, Co1, mode;
};

__global__ __launch_bounds__(256, 4) void conv3_k(C3Args A)
{
    const int cumT[5] = {200, 250, 265, 271, 273};
    const int txA[5]  = {10, 5, 3, 2, 1};
    const int Wt[5]   = {80, 40, 20, 10, 5};
    const int pxB[5]  = {0, 6400, 8000, 8400, 8500};

    __shared__ __align__(16) _Float16 Xs[60 * 72];   // 6x10 px * (32hi|32lo|8pad)

    const int gid = blockIdx.x;
    int head, coGrp, t;
    if (A.mode == 0) {
        int oct = gid & 7; head = oct >> 2; int tq = oct & 3;
        int p = gid >> 3; coGrp = p & 1; int tl = p >> 1;
        t = tq * 69 + tl;
    } else {
        int oct = gid & 7; int tq = oct & 3; int ch = oct >> 2;
        int p = gid >> 3; int ci = p & 3; int tl = p >> 2;
        int combo = ch * 4 + ci;
        if (combo >= 7) return;
        head = (combo == 6) ? 1 : 0;
        coGrp = (combo == 6) ? 0 : combo;
        t = tq * 69 + tl;
    }
    if (t >= 273) return;

    int lv = 0; while (t >= cumT[lv]) lv++;
    const int tile = t - (lv ? cumT[lv - 1] : 0);
    const int W = Wt[lv], HW = W * W;
    const int tx = txA[lv];
    const int tyi = tile / tx, txi = tile - tyi * tx;
    const int x0 = txi * 8, y0 = tyi * 4;

    const _Float16* aIn = (head ? A.aIn1 : A.aIn0) + (size_t)pxB[lv] * 512;
    const _Float16* wp  = head ? A.wp1 : A.wp0;
    const float* bias   = head ? A.bias1 : A.bias0;
    const int CoPad     = head ? A.CoPad1 : A.CoPad0;
    const int Co        = head ? A.Co1 : A.Co0;
    const int NC16      = CoPad >> 4;

    const int tid = threadIdx.x;
    const int w = tid >> 6, lane = tid & 63;
    const int l15 = lane & 15, quad = lane >> 4;
    const int coW = coGrp * 128 + w * 32;
    const bool active = coW < CoPad;         // reg waves 2,3 idle
    const int c16b = coW >> 4;

    float4v acc[2][2];
#pragma unroll
    for (int i = 0; i < 2; i++)
#pragma unroll
        for (int j = 0; j < 2; j++) acc[i][j] = (float4v){0.f, 0.f, 0.f, 0.f};

    const half8 z8 = {(_Float16)0, (_Float16)0, (_Float16)0, (_Float16)0,
                      (_Float16)0, (_Float16)0, (_Float16)0, (_Float16)0};

    // ---- staging precompute (addresses invariant across cc chunks)
    const int u0 = tid, u1 = tid + 256;
    const int px0 = u0 >> 3, sg0 = u0 & 7;
    const int rA = px0 / 10, cA = px0 - rA * 10;
    const int gy0 = y0 + rA - 1, gx0 = x0 + cA - 1;
    const bool v0ok = (gy0 >= 0) && (gy0 < W) && (gx0 >= 0) && (gx0 < W);
    const _Float16* ga0 = aIn + (size_t)(v0ok ? (gy0 * W + gx0) : 0) * 512
                          + ((sg0 < 4) ? sg0 * 8 : 256 + (sg0 - 4) * 8);
    _Float16* ls0 = Xs + px0 * 72 + ((sg0 & 4) ? 32 : 0) + ((((sg0 & 3) + px0) & 3) * 8);

    const bool u1v = u1 < 480;
    const int px1 = u1 >> 3, sg1 = u1 & 7;
    const int rB = px1 / 10, cB = px1 - rB * 10;
    const int gy1 = y0 + rB - 1, gx1 = x0 + cB - 1;
    const bool v1ok = u1v && (gy1 >= 0) && (gy1 < W) && (gx1 >= 0) && (gx1 < W);
    const _Float16* ga1 = aIn + (size_t)(v1ok ? (gy1 * W + gx1) : 0) * 512
                          + ((sg1 < 4) ? sg1 * 8 : 256 + (sg1 - 4) * 8);
    _Float16* ls1 = Xs + px1 * 72 + ((sg1 & 4) ? 32 : 0) + ((((sg1 & 3) + px1) & 3) * 8);

    half8 st0 = v0ok ? *(const half8*)ga0 : z8;     // chunk 0 prefetch
    half8 st1 = v1ok ? *(const half8*)ga1 : z8;

    const size_t wsplit = (size_t)4096 * NC16;      // hi->lo element offset
    auto loadB = [&](int cc, int tap, half8* bh, half8* bl) {
#pragma unroll
        for (int nf = 0; nf < 2; nf++) {
            const _Float16* wb = wp +
                ((((size_t)(tap * 2) * 8 + cc) * NC16 + c16b + nf) * 64 + lane) * 8;
            bh[nf] = *(const half8*)wb;
            bl[nf] = *(const half8*)(wb + wsplit);
        }
    };

    half8 bhc[2], blc[2], bhn[2], bln[2];
    if (active) loadB(0, 0, bhc, blc);

    for (int cc = 0; cc < 8; cc++) {
        __syncthreads();
        *(half8*)ls0 = st0;
        if (u1v) *(half8*)ls1 = st1;
        __syncthreads();
        if (cc < 7) {   // prefetch next chunk's acts during this chunk's compute
            st0 = v0ok ? *(const half8*)(ga0 + (cc + 1) * 32) : z8;
            st1 = v1ok ? *(const half8*)(ga1 + (cc + 1) * 32) : z8;
        }

        if (active) {
            for (int tap = 0; tap < 9; tap++) {
                const int dy = tap / 3 - 1, dx = tap % 3 - 1;
                half8 ah[2], al[2];
#pragma unroll
                for (int mf = 0; mf < 2; mf++) {
                    int lpx = (2 * mf + (l15 >> 3) + 1 + dy) * 10 + (l15 & 7) + 1 + dx;
                    const _Float16* lp = Xs + lpx * 72 + (((quad + lpx) & 3) * 8);
                    ah[mf] = *(const half8*)lp;
                    al[mf] = *(const half8*)(lp + 32);
                }
                if (tap < 8) loadB(cc, tap + 1, bhn, bln);
                else if (cc < 7) loadB(cc + 1, 0, bhn, bln);
#pragma unroll
                for (int nf = 0; nf < 2; nf++) {
#pragma unroll
                    for (int mf = 0; mf < 2; mf++) {
                        acc[mf][nf] = __builtin_amdgcn_mfma_f32_16x16x32_f16(ah[mf], bhc[nf], acc[mf][nf], 0, 0, 0);
                        acc[mf][nf] = __builtin_amdgcn_mfma_f32_16x16x32_f16(ah[mf], blc[nf], acc[mf][nf], 0, 0, 0);
                        acc[mf][nf] = __builtin_amdgcn_mfma_f32_16x16x32_f16(al[mf], bhc[nf], acc[mf][nf], 0, 0, 0);
                    }
                }
#pragma unroll
                for (int nf = 0; nf < 2; nf++) { bhc[nf] = bhn[nf]; blc[nf] = bln[nf]; }
            }
        }
    }

    if (!active) return;

    int coN[2];
    float bv[2];
#pragma unroll
    for (int nf = 0; nf < 2; nf++) {
        coN[nf] = coW + nf * 16 + l15;
        bv[nf] = (coN[nf] < Co) ? bias[coN[nf]] : 0.f;
    }

    // C layout: m = quad*4 + r -> y = y0 + 2*mf + (m>>3), x = x0 + (m&7)
    if (A.mode == 0) {
        _Float16* ao = (head ? A.aOut1 : A.aOut0) + (size_t)pxB[lv] * 512;
#pragma unroll
        for (int nf = 0; nf < 2; nf++) {
#pragma unroll
            for (int mf = 0; mf < 2; mf++) {
#pragma unroll
                for (int r = 0; r < 4; r++) {
                    int m = quad * 4 + r;
                    int yy = y0 + 2 * mf + (m >> 3);
                    int xx = x0 + (m & 7);
                    if (yy < W && xx < W) {
                        int px = yy * W + xx;
                        float v = fmaxf(acc[mf][nf][r] + bv[nf], 0.f);
                        _Float16 h = (_Float16)v;
                        _Float16 lo = (_Float16)(v - (float)h);
                        ao[(size_t)px * 512 + coN[nf]] = h;
                        ao[(size_t)px * 512 + 256 + coN[nf]] = lo;
                    }
                }
            }
        }
    } else {
        float* ho = (head ? A.hOut1 : A.hOut0) + (size_t)Co * pxB[lv];
#pragma unroll
        for (int nf = 0; nf < 2; nf++) {
            if (coN[nf] < Co) {
                float* col = ho + (size_t)coN[nf] * HW;
#pragma unroll
                for (int mf = 0; mf < 2; mf++) {
#pragma unroll
                    for (int r = 0; r < 4; r++) {
                        int m = quad * 4 + r;
                        int yy = y0 + 2 * mf + (m >> 3);
                        int xx = x0 + (m & 7);
                        if (yy < W && xx < W) col[yy * W + xx] = acc[mf][nf][r] + bv[nf];
                    }
                }
            }
        }
    }
}

// ---------------------------------------------------------------- cls reduce
// argmax MUST be in fp32 sigmoid domain: saturated classes tie at 1.0f and
// jnp.argmax picks the lowest tied class index (logit-domain argmax differs).
__global__ void cls_reduce_k(const float* __restrict__ ho,
                             u64* __restrict__ keys, int* __restrict__ cls_all)
{
    const int cumB[5] = {225, 282, 297, 301, 302};
    const int HWs[5]  = {6400, 1600, 400, 100, 25};
    const int pxB[5]  = {0, 6400, 8000, 8400, 8500};
    const int offs[5] = {0, 57600, 72000, 75600, 76500};
    int b = blockIdx.x;
    int lv = 0;
    while (b >= cumB[lv]) lv++;
    int local = (b - (lv ? cumB[lv - 1] : 0)) * 256 + threadIdx.x;
    const int HW = HWs[lv];
    if (local >= HW * 9) return;
    int a = local / HW, p = local - a * HW;
    const float* base = ho + (size_t)720 * pxB[lv] + (size_t)a * 80 * HW + p;
    float m = -1.f; int arg = 0;
    for (int c = 0; c < 80; c++) {
        float logit = base[(size_t)c * HW];
        float s = 1.0f / (1.0f + expf(-logit));
        if (s > m) { m = s; arg = c; }
    }
    float masked = (m > 0.05f) ? m : -1.0f;
    unsigned u = __float_as_uint(masked);
    unsigned su = (u & 0x80000000u) ? ~u : (u | 0x80000000u);
    int g = offs[lv] + p * 9 + a;
    keys[g] = ((u64)su << 32) | (u64)(0xFFFFFFFFu - (unsigned)g);
    cls_all[g] = arg;
}

// ---------------------------------------------------------------- decode
struct DecArgs { float aw[45]; float ah[45]; };

__global__ void decode_k(const float* __restrict__ ro, DecArgs D, float* __restrict__ boxes_all)
{
    const int cumB[5] = {225, 282, 297, 301, 302};
    const int HWs[5]  = {6400, 1600, 400, 100, 25};
    const int Wt[5]   = {80, 40, 20, 10, 5};
    const int pxB[5]  = {0, 6400, 8000, 8400, 8500};
    const int offs[5] = {0, 57600, 72000, 75600, 76500};
    const float strd[5] = {8.f, 16.f, 32.f, 64.f, 128.f};
    int b = blockIdx.x;
    int lv = 0;
    while (b >= cumB[lv]) lv++;
    int local = (b - (lv ? cumB[lv - 1] : 0)) * 256 + threadIdx.x;
    const int HW = HWs[lv], W = Wt[lv];
    if (local >= HW * 9) return;
    int a = local / HW, p = local - a * HW;
    int y = p / W, x = p - y * W;
    float cx0 = ((float)x + 0.5f) * strd[lv];
    float cy0 = ((float)y + 0.5f) * strd[lv];
    float aw = D.aw[lv * 9 + a], ahh = D.ah[lv * 9 + a];
    float ax1 = cx0 - aw * 0.5f, ax2 = cx0 + aw * 0.5f;
    float ay1 = cy0 - ahh * 0.5f, ay2 = cy0 + ahh * 0.5f;
    float w = ax2 - ax1, h = ay2 - ay1;
    float cx = ax1 + 0.5f * w, cy = ay1 + 0.5f * h;
    const float* base = ro + (size_t)36 * pxB[lv] + p;
    float l0 = base[(size_t)(a * 4 + 0) * HW];
    float l1 = base[(size_t)(a * 4 + 1) * HW];
    float l2 = base[(size_t)(a * 4 + 2) * HW];
    float l3 = base[(size_t)(a * 4 + 3) * HW];
    float dx = l0 * 0.1f, dy = l1 * 0.1f, dw = l2 * 0.2f, dh = l3 * 0.2f;
    float pcx = cx + dx * w, pcy = cy + dy * h;
    float pw = expf(dw) * w, ph = expf(dh) * h;
    float bx1 = fminf(fmaxf(pcx - 0.5f * pw, 0.f), 640.f);
    float by1 = fminf(fmaxf(pcy - 0.5f * ph, 0.f), 640.f);
    float bx2 = fminf(fmaxf(pcx + 0.5f * pw, 0.f), 640.f);
    float by2 = fminf(fmaxf(pcy + 0.5f * ph, 0.f), 640.f);
    int g = offs[lv] + p * 9 + a;
    boxes_all[g * 4 + 0] = bx1;
    boxes_all[g * 4 + 1] = by1;
    boxes_all[g * 4 + 2] = bx2;
    boxes_all[g * 4 + 3] = by2;
}

__global__ void pad_keys_k(u64* __restrict__ keys)
{
    int i = blockIdx.x * blockDim.x + threadIdx.x + NANCH;
    if (i < NPAD) keys[i] = 0ULL;
}

// ---------------------------------------------------------------- sort
__global__ __launch_bounds__(1024) void chunk_sort_desc_k(u64* __restrict__ keys)
{
    __shared__ u64 s[4096];
    const int base = blockIdx.x * 4096;
    for (int i = threadIdx.x; i < 4096; i += 1024) s[i] = keys[base + i];
    __syncthreads();
    for (int size = 2; size <= 4096; size <<= 1) {
        for (int stride = size >> 1; stride > 0; stride >>= 1) {
            for (int t = threadIdx.x; t < 2048; t += 1024) {
                int low = t & (stride - 1);
                int i = ((t - low) << 1) | low;
                int j = i + stride;
                bool desc = ((i & size) == 0);
                u64 a = s[i], b = s[j];
                if (desc ? (a < b) : (a > b)) { s[i] = b; s[j] = a; }
            }
            __syncthreads();
        }
    }
    for (int i = threadIdx.x; i < 4096; i += 1024) keys[base + i] = s[i];
}

__global__ __launch_bounds__(1024) void gather_top_k(const u64* __restrict__ keys,
                                                     u64* __restrict__ keys2)
{
    int i = blockIdx.x * 1024 + threadIdx.x;
    keys2[i] = keys[(i >> 10) * 4096 + (i & 1023)];
}

__global__ void bitonic_global_k(u64* __restrict__ keys, int size, int stride)
{
    int t = blockIdx.x * blockDim.x + threadIdx.x;
    int low = t & (stride - 1);
    int i = ((t - low) << 1) | low;
    int j = i + stride;
    bool desc = ((i & size) == 0);
    u64 a = keys[i], b = keys[j];
    if (desc ? (a < b) : (a > b)) { keys[i] = b; keys[j] = a; }
}

__global__ __launch_bounds__(1024) void bitonic_local_full_k(u64* __restrict__ keys)
{
    __shared__ u64 s[4096];
    const int base = blockIdx.x * 4096;
    for (int i = threadIdx.x; i < 4096; i += 1024) s[i] = keys[base + i];
    __syncthreads();
    for (int size = 2; size <= 4096; size <<= 1) {
        for (int stride = size >> 1; stride > 0; stride >>= 1) {
            for (int t = threadIdx.x; t < 2048; t += 1024) {
                int low = t & (stride - 1);
                int i = ((t - low) << 1) | low;
                int j = i + stride;
                bool desc = (((base + i) & size) == 0);
                u64 a = s[i], b = s[j];
                if (desc ? (a < b) : (a > b)) { s[i] = b; s[j] = a; }
            }
            __syncthreads();
        }
    }
    for (int i = threadIdx.x; i < 4096; i += 1024) keys[base + i] = s[i];
}

__global__ __launch_bounds__(1024) void bitonic_local_k(u64* __restrict__ keys, int size)
{
    __shared__ u64 s[4096];
    const int base = blockIdx.x * 4096;
    for (int i = threadIdx.x; i < 4096; i += 1024) s[i] = keys[base + i];
    __syncthreads();
    const bool desc = ((base & size) == 0);
    for (int stride = 2048; stride > 0; stride >>= 1) {
        for (int t = threadIdx.x; t < 2048; t += 1024) {
            int low = t & (stride - 1);
            int i = ((t - low) << 1) | low;
            int j = i + stride;
            u64 a = s[i], b = s[j];
            if (desc ? (a < b) : (a > b)) { s[i] = b; s[j] = a; }
        }
        __syncthreads();
    }
    for (int i = threadIdx.x; i < 4096; i += 1024) keys[base + i] = s[i];
}

// ---------------------------------------------------------------- NMS (mask-based)
__global__ void gather_cand_k(const u64* __restrict__ keys,
                              const float* __restrict__ boxes_all,
                              const int* __restrict__ cls_all,
                              float* __restrict__ cand)
{
    int i = blockIdx.x * 256 + threadIdx.x;
    if (i >= 1000) return;
    u64 k = keys[i];
    unsigned shi = (unsigned)(k >> 32);
    unsigned u = (shi & 0x80000000u) ? (shi ^ 0x80000000u) : ~shi;
    float val = __uint_as_float(u);
    int anchor = (int)(0xFFFFFFFFu - (unsigned)(k & 0xFFFFFFFFull));
    float x1 = boxes_all[anchor * 4 + 0];
    float y1 = boxes_all[anchor * 4 + 1];
    float x2 = boxes_all[anchor * 4 + 2];
    float y2 = boxes_all[anchor * 4 + 3];
    cand[i * 8 + 0] = x1;
    cand[i * 8 + 1] = y1;
    cand[i * 8 + 2] = x2;
    cand[i * 8 + 3] = y2;
    cand[i * 8 + 4] = fmaxf(x2 - x1, 0.f) * fmaxf(y2 - y1, 0.f);
    cand[i * 8 + 5] = val;
    cand[i * 8 + 6] = (float)cls_all[anchor];
    cand[i * 8 + 7] = (val > 0.0f) ? 1.f : 0.f;
}

__global__ __launch_bounds__(256) void iou_mask_k(const float* __restrict__ cand,
                                                  u64* __restrict__ mask)
{
    const int i = blockIdx.x;
    const float x1 = cand[i * 8 + 0], y1 = cand[i * 8 + 1];
    const float x2 = cand[i * 8 + 2], y2 = cand[i * 8 + 3];
    const float ar = cand[i * 8 + 4];
    const int tid = threadIdx.x;
    const int wave = tid >> 6, lane = tid & 63;
    for (int base = 0; base < 1024; base += 256) {
        int j = base + tid;
        bool sup = false;
        if (j < 1000 && j > i) {
            float jx1 = cand[j * 8 + 0], jy1 = cand[j * 8 + 1];
            float jx2 = cand[j * 8 + 2], jy2 = cand[j * 8 + 3];
            float jar = cand[j * 8 + 4];
            float xx1 = fmaxf(x1, jx1), yy1 = fmaxf(y1, jy1);
            float xx2 = fminf(x2, jx2), yy2 = fminf(y2, jy2);
            float inter = fmaxf(xx2 - xx1, 0.f) * fmaxf(yy2 - yy1, 0.f);
            float iou = inter / (ar + jar - inter + 1e-8f);
            sup = iou > 0.5f;
        }
        u64 ball = __ballot(sup);
        int word = (base >> 6) + wave;
        if (lane == 0) mask[(size_t)i * 16 + word] = ball;
    }
}

// Tiled register sweep: 16 tiles of 64. Mirrored suppressed word per tile
// (identical in all lanes) -> alive test is a LOCAL register op; the only
// cross-lane ops (shfl of row words, ballot, or-reduce) are independent of
// the serial chain. Exactly reproduces the reference greedy order.
__global__ __launch_bounds__(64) void nms_sweep_out_k(const float* __restrict__ cand,
                                                      const u64* __restrict__ M,
                                                      float* __restrict__ out)
{
    const int lane = threadIdx.x;

    u64 V[16];
#pragma unroll
    for (int t = 0; t < 16; t++) {
        int i = t * 64 + lane;
        bool v = (i < 1000) && (cand[i * 8 + 7] > 0.f);
        V[t] = __ballot(v);
    }

    u64 pend[16];
#pragma unroll
    for (int t = 0; t < 16; t++) pend[t] = 0;
    u64 aliveW[16];

    for (int T = 0; T < 16; T++) {
        u64 rw[16];
        int row = T * 64 + lane;
        for (int t = T; t < 16; t++)
            rw[t] = (row < 1000) ? M[(size_t)row * 16 + t] : 0ULL;

        u64 s = pend[T];
        u64 alive = 0;
        u64 myw = rw[T];
        const u64 VT = V[T];
#pragma unroll
        for (int i = 0; i < 64; i++) {
            u64 ri = __shfl(myw, i);
            bool a = ((VT >> i) & 1) && !((s >> i) & 1);
            if (a) { s |= ri; alive |= (1ULL << i); }
        }
        aliveW[T] = alive;

        for (int t = T + 1; t < 16; t++) {
            u64 c = ((alive >> lane) & 1) ? rw[t] : 0ULL;
#pragma unroll
            for (int d = 1; d < 64; d <<= 1) c |= __shfl_xor(c, d);
            pend[t] |= c;
        }
    }

    for (int i = lane; i < 1000; i += 64) {
        int kp = (int)((aliveW[i >> 6] >> (i & 63)) & 1);
        float m = kp ? 1.f : 0.f;
        out[i] = kp ? cand[i * 8 + 5] : 0.f;
        out[1000 + i] = cand[i * 8 + 6];
        out[2000 + i * 4 + 0] = m * cand[i * 8 + 0];
        out[2000 + i * 4 + 1] = m * cand[i * 8 + 1];
        out[2000 + i * 4 + 2] = m * cand[i * 8 + 2];
        out[2000 + i * 4 + 3] = m * cand[i * 8 + 3];
        out[6000 + i] = m;
    }
}

// ---------------------------------------------------------------- host
extern "C" void kernel_launch(void* const* d_in, const int* in_sizes, int n_in,
                              void* d_out, int out_size, void* d_ws, size_t ws_size,
                              hipStream_t stream)
{
    const float* feats[5];
    for (int i = 0; i < 5; i++) feats[i] = (const float*)d_in[i];
    const float* cls_w  = (const float*)d_in[5];
    const float* cls_b  = (const float*)d_in[6];
    const float* cls_hw = (const float*)d_in[7];
    const float* cls_hb = (const float*)d_in[8];
    const float* reg_w  = (const float*)d_in[9];
    const float* reg_b  = (const float*)d_in[10];
    const float* reg_hw = (const float*)d_in[11];
    const float* reg_hb = (const float*)d_in[12];
    float* out = (float*)d_out;

    // ---------- workspace layout
    char* ws = (char*)d_ws;
    size_t off = 0;
    auto alloc = [&](size_t sz) { size_t o = off; off += (sz + 255) & ~(size_t)255; return o; };

    size_t R0 = alloc((size_t)(HEADC_EL + HEADR_EL) * 4);   // headout / act2_feats overlay
    _Float16* act2_feats = (_Float16*)(ws + R0);
    float* headout_cls = (float*)(ws + R0);
    float* headout_reg = headout_cls + HEADC_EL;

    _Float16* a2_clsA = (_Float16*)(ws + alloc(ACT2_EL * 2));
    _Float16* a2_regA = (_Float16*)(ws + alloc(ACT2_EL * 2));
    _Float16* a2_clsB = (_Float16*)(ws + alloc(ACT2_EL * 2));
    _Float16* a2_regB = (_Float16*)(ws + alloc(ACT2_EL * 2));

    _Float16* wpc[4]; _Float16* wpr[4];
    for (int i = 0; i < 4; i++) wpc[i] = (_Float16*)(ws + alloc((size_t)TRUNK_WP_EL * 2));
    _Float16* wpch = (_Float16*)(ws + alloc((size_t)CLSH_WP_EL * 2));
    for (int i = 0; i < 4; i++) wpr[i] = (_Float16*)(ws + alloc((size_t)TRUNK_WP_EL * 2));
    _Float16* wprh = (_Float16*)(ws + alloc((size_t)REGH_WP_EL * 2));

    u64* keys  = (u64*)(ws + alloc((size_t)NPAD * 8));
    u64* keys2 = (u64*)(ws + alloc((size_t)NPAD2 * 8));
    float* boxes_all = (float*)(ws + alloc((size_t)NANCH * 16));
    int* cls_all = (int*)(ws + alloc((size_t)NANCH * 4));
    float* cand = (float*)(ws + alloc((size_t)1000 * 8 * 4));
    u64* mask = (u64*)(ws + alloc((size_t)1000 * 16 * 8));
    (void)ws_size;

    // ---------- weight prep
    PrepArgs P;
    long cum = 0;
    for (int e = 0; e < 10; e++) {
        const float* src; _Float16* dst; int Co, NC16;
        if (e < 4)      { src = cls_w + (size_t)e * 589824; dst = wpc[e]; Co = 256; NC16 = 16; }
        else if (e == 4){ src = cls_hw;                     dst = wpch;   Co = 720; NC16 = 48; }
        else if (e < 9) { src = reg_w + (size_t)(e - 5) * 589824; dst = wpr[e - 5]; Co = 256; NC16 = 16; }
        else            { src = reg_hw;                     dst = wprh;   Co = 36;  NC16 = 4; }
        P.src[e] = src; P.dst[e] = dst; P.Co[e] = Co; P.NC16[e] = NC16;
        P.base[e] = cum; cum += (long)9216 * NC16;
    }
    P.base[10] = cum;
    prep_k<<<(int)((cum + 255) / 256), 256, 0, stream>>>(P);

    pad_keys_k<<<(NPAD - NANCH + 255) / 256, 256, 0, stream>>>(keys);

    // ---------- feats repack
    RepArgs R;
    for (int lv = 0; lv < 5; lv++) R.src[lv] = feats[lv];
    R.dst = act2_feats;
    repack_k<<<135, 256, 0, stream>>>(R);

    // ---------- conv layers
    auto trunk = [&](const _Float16* i0, const _Float16* i1, _Float16* o0, _Float16* o1,
                     const _Float16* w0, const _Float16* w1, const float* b0, const float* b1) {
        C3Args C;
        C.aIn0 = i0; C.aIn1 = i1; C.aOut0 = o0; C.aOut1 = o1;
        C.hOut0 = nullptr; C.hOut1 = nullptr;
        C.wp0 = w0; C.wp1 = w1; C.bias0 = b0; C.bias1 = b1;
        C.CoPad0 = 256; C.CoPad1 = 256;
        C.Co0 = 256; C.Co1 = 256; C.mode = 0;
        conv3_k<<<8 * 2 * 69, 256, 0, stream>>>(C);
    };
    trunk(act2_feats, act2_feats, a2_clsA, a2_regA, wpc[0], wpr[0], cls_b + 0,   reg_b + 0);
    trunk(a2_clsA,    a2_regA,    a2_clsB, a2_regB, wpc[1], wpr[1], cls_b + 256, reg_b + 256);
    trunk(a2_clsB,    a2_regB,    a2_clsA, a2_regA, wpc[2], wpr[2], cls_b + 512, reg_b + 512);
    trunk(a2_clsA,    a2_regA,    a2_clsB, a2_regB, wpc[3], wpr[3], cls_b + 768, reg_b + 768);

    {   // head convs: combos 0..5 = cls 128-co groups, 6 = reg (2 active waves)
        C3Args C;
        C.aIn0 = a2_clsB; C.aIn1 = a2_regB;
        C.aOut0 = nullptr; C.aOut1 = nullptr;
        C.hOut0 = headout_cls; C.hOut1 = headout_reg;
        C.wp0 = wpch; C.wp1 = wprh; C.bias0 = cls_hb; C.bias1 = reg_hb;
        C.CoPad0 = 768; C.CoPad1 = 64;
        C.Co0 = 720; C.Co1 = 36; C.mode = 1;
        conv3_k<<<8 * 4 * 69, 256, 0, stream>>>(C);
    }

    // ---------- reduce + decode
    cls_reduce_k<<<302, 256, 0, stream>>>(headout_cls, keys, cls_all);

    DecArgs D;
    {
        const float sz[5] = {32.f, 64.f, 128.f, 256.f, 512.f};
        const float ratios[3] = {0.5f, 1.0f, 2.0f};
        const float scales[3] = {1.0f, 1.25992104989487316477f, 1.58740105196819947475f};
        for (int lv = 0; lv < 5; lv++)
            for (int r = 0; r < 3; r++)
                for (int s = 0; s < 3; s++) {
                    D.aw[lv * 9 + r * 3 + s] = sz[lv] * scales[s] / sqrtf(ratios[r]);
                    D.ah[lv * 9 + r * 3 + s] = sz[lv] * scales[s] * sqrtf(ratios[r]);
                }
    }
    decode_k<<<302, 256, 0, stream>>>(headout_reg, D, boxes_all);

    // ---------- top-K sort
    chunk_sort_desc_k<<<NPAD / 4096, 1024, 0, stream>>>(keys);
    gather_top_k<<<NPAD2 / 1024, 1024, 0, stream>>>(keys, keys2);
    bitonic_local_full_k<<<NPAD2 / 4096, 1024, 0, stream>>>(keys2);
    for (int size = 8192; size <= NPAD2; size <<= 1) {
        for (int stride = size >> 1; stride >= 4096; stride >>= 1)
            bitonic_global_k<<<NPAD2 / 2 / 1024, 1024, 0, stream>>>(keys2, size, stride);
        bitonic_local_k<<<NPAD2 / 4096, 1024, 0, stream>>>(keys2, size);
    }

    // ---------- NMS
    gather_cand_k<<<4, 256, 0, stream>>>(keys2, boxes_all, cls_all, cand);
    iou_mask_k<<<1000, 256, 0, stream>>>(cand, mask);
    nms_sweep_out_k<<<1, 64, 0, stream>>>(cand, mask, out);
}

// Round 11
// 849.497 us; speedup vs baseline: 1.2532x; 1.2532x over previous
//
#include <hip/hip_runtime.h>
#include <math.h>
#include <stdint.h>

#define NANCH 76725
#define NPAD  131072
#define NPAD2 32768
#define PXTOT 8525

typedef _Float16 half8 __attribute__((ext_vector_type(8)));
typedef _Float16 half4 __attribute__((ext_vector_type(4)));
typedef float float4v __attribute__((ext_vector_type(4)));
typedef unsigned long long u64;

#define ACT2_EL  ((size_t)PXTOT * 512)     // [px][hi256|lo256] fp16
#define HEADC_EL (720 * PXTOT)
#define HEADR_EL (36 * PXTOT)

// prepped weight element counts (fp16): [tap9][split2][ciChunk8][co16][lane64][8]
#define TRUNK_WP_EL (9 * 2 * 8 * 16 * 64 * 8)    // NC16=16
#define CLSH_WP_EL  (9 * 2 * 8 * 48 * 64 * 8)    // NC16=48
#define REGH_WP_EL  (9 * 2 * 8 * 4 * 64 * 8)     // NC16=4

// ---------------------------------------------------------------- weight prep
// dst layout: B-fragment-native. frag(tap,s,cc,c16) = 1KB contiguous:
//   lane l: co = c16*16 + (l&15), ci = cc*32 + (l>>4)*8 + j  (j=0..7)
struct PrepArgs {
    const float* src[10];
    _Float16*    dst[10];
    int Co[10], NC16[10];
    long base[11];
};

__global__ __launch_bounds__(256) void prep_k(PrepArgs P)
{
    long idx = (long)blockIdx.x * 256 + threadIdx.x;
    if (idx >= P.base[10]) return;
    int e = 0;
    while (idx >= P.base[e + 1]) e++;
    long local = idx - P.base[e];
    const int NC16 = P.NC16[e], Co = P.Co[e];
    int lane = (int)(local & 63);
    long t2 = local >> 6;
    int c16 = (int)(t2 % NC16);
    long t3 = t2 / NC16;
    int cc = (int)(t3 & 7);
    int t4 = (int)(t3 >> 3);          // 0..17
    int s = t4 & 1, tap = t4 >> 1;
    int co = c16 * 16 + (lane & 15);
    int kb = cc * 32 + (lane >> 4) * 8;
    const float* src = P.src[e];
    half8 out;
#pragma unroll
    for (int j = 0; j < 8; j++) {
        float v = (co < Co) ? src[(size_t)(co * 256 + kb + j) * 9 + tap] : 0.f;
        _Float16 h = (_Float16)v;
        out[j] = s ? (_Float16)(v - (float)h) : h;
    }
    _Float16* dst = P.dst[e] + ((((size_t)(tap * 2 + s) * 8 + cc) * NC16 + c16) * 64 + lane) * 8;
    *(half8*)dst = out;
}

// ---------------------------------------------------------------- feats repack
// feats fp32 [256][HW] -> act2 [px][hi256|lo256] fp16
struct RepArgs { const float* src[5]; _Float16* dst; };

__global__ __launch_bounds__(256) void repack_k(RepArgs R)
{
    __shared__ float T[64][257];
    const int cumT[5] = {100, 125, 132, 134, 135};
    const int Wt[5]   = {80, 40, 20, 10, 5};
    const int pxB[5]  = {0, 6400, 8000, 8400, 8500};
    int t = blockIdx.x;
    int lv = 0; while (t >= cumT[lv]) lv++;
    int tile = t - (lv ? cumT[lv - 1] : 0);
    const int HW = Wt[lv] * Wt[lv];
    const int pxStart = tile * 64;
    const float* src = R.src[lv];
    const int tid = threadIdx.x, w = tid >> 6, l6 = tid & 63;
    int p = pxStart + l6;
    bool ok = p < HW;
    for (int ci = w; ci < 256; ci += 4)
        T[l6][ci] = ok ? src[(size_t)ci * HW + p] : 0.f;
    __syncthreads();
    _Float16* dst = R.dst + (size_t)pxB[lv] * 512;
    for (int px = w; px < 64; px += 4) {
        int pp = pxStart + px;
        if (pp >= HW) continue;
        half4 h, l;
#pragma unroll
        for (int j = 0; j < 4; j++) {
            float v = T[px][l6 * 4 + j];
            _Float16 hh = (_Float16)v;
            h[j] = hh; l[j] = (_Float16)(v - (float)hh);
        }
        *(half4*)(dst + (size_t)pp * 512 + l6 * 4) = h;
        *(half4*)(dst + (size_t)pp * 512 + 256 + l6 * 4) = l;
    }
}

// ---------------------------------------------------------------- conv
// 4-wave blocks: 8x4 px tile, shared 6x10 halo in LDS; wave w -> 32 co.
// Tap loop fully unrolled -> compiler hoists B-loads (many vmcnt in flight).
// LDS slot key (quad + (lpx>>3))&3 breaks the dRow=8 bank alias (r10's
// (quad+lpx)&3 was a no-op: 8 = 0 mod 4 -> conflicts bit-identical).
// Act staging for chunk cc+1 prefetched into regs during chunk cc compute.
struct C3Args {
    const _Float16* aIn0; const _Float16* aIn1;
    _Float16* aOut0; _Float16* aOut1;     // trunk (mode=0)
    float* hOut0; float* hOut1;           // head (mode=1), layout [co][px]
    const _Float16* wp0; const _Float16* wp1;
    const float* bias0; const float* bias1;
    int CoPad0, CoPad1, Co0, Co1, mode;
};

__global__ __launch_bounds__(256, 3) void conv3_k(C3Args A)
{
    const int cumT[5] = {200, 250, 265, 271, 273};
    const int txA[5]  = {10, 5, 3, 2, 1};
    const int Wt[5]   = {80, 40, 20, 10, 5};
    const int pxB[5]  = {0, 6400, 8000, 8400, 8500};

    __shared__ __align__(16) _Float16 Xs[60 * 72];   // 6x10 px * (32hi|32lo|8pad)

    const int gid = blockIdx.x;
    int head, coGrp, t;
    if (A.mode == 0) {
        int oct = gid & 7; head = oct >> 2; int tq = oct & 3;
        int p = gid >> 3; coGrp = p & 1; int tl = p >> 1;
        t = tq * 69 + tl;
    } else {
        int oct = gid & 7; int tq = oct & 3; int ch = oct >> 2;
        int p = gid >> 3; int ci = p & 3; int tl = p >> 2;
        int combo = ch * 4 + ci;
        if (combo >= 7) return;
        head = (combo == 6) ? 1 : 0;
        coGrp = (combo == 6) ? 0 : combo;
        t = tq * 69 + tl;
    }
    if (t >= 273) return;

    int lv = 0; while (t >= cumT[lv]) lv++;
    const int tile = t - (lv ? cumT[lv - 1] : 0);
    const int W = Wt[lv], HW = W * W;
    const int tx = txA[lv];
    const int tyi = tile / tx, txi = tile - tyi * tx;
    const int x0 = txi * 8, y0 = tyi * 4;

    const _Float16* aIn = (head ? A.aIn1 : A.aIn0) + (size_t)pxB[lv] * 512;
    const _Float16* wp  = head ? A.wp1 : A.wp0;
    const float* bias   = head ? A.bias1 : A.bias0;
    const int CoPad     = head ? A.CoPad1 : A.CoPad0;
    const int Co        = head ? A.Co1 : A.Co0;
    const int NC16      = CoPad >> 4;

    const int tid = threadIdx.x;
    const int w = tid >> 6, lane = tid & 63;
    const int l15 = lane & 15, quad = lane >> 4;
    const int coW = coGrp * 128 + w * 32;
    const bool active = coW < CoPad;         // reg waves 2,3 idle
    const int c16b = coW >> 4;

    float4v acc[2][2];
#pragma unroll
    for (int i = 0; i < 2; i++)
#pragma unroll
        for (int j = 0; j < 2; j++) acc[i][j] = (float4v){0.f, 0.f, 0.f, 0.f};

    const half8 z8 = {(_Float16)0, (_Float16)0, (_Float16)0, (_Float16)0,
                      (_Float16)0, (_Float16)0, (_Float16)0, (_Float16)0};

    // ---- staging precompute (addresses invariant across cc chunks)
    const int u0 = tid, u1 = tid + 256;
    const int px0 = u0 >> 3, sg0 = u0 & 7;
    const int rA = px0 / 10, cA = px0 - rA * 10;
    const int gy0 = y0 + rA - 1, gx0 = x0 + cA - 1;
    const bool v0ok = (gy0 >= 0) && (gy0 < W) && (gx0 >= 0) && (gx0 < W);
    const _Float16* ga0 = aIn + (size_t)(v0ok ? (gy0 * W + gx0) : 0) * 512
                          + ((sg0 < 4) ? sg0 * 8 : 256 + (sg0 - 4) * 8);
    _Float16* ls0 = Xs + px0 * 72 + ((sg0 & 4) ? 32 : 0)
                    + ((((sg0 & 3) + (px0 >> 3)) & 3) * 8);

    const bool u1v = u1 < 480;
    const int px1 = u1 >> 3, sg1 = u1 & 7;
    const int rB = px1 / 10, cB = px1 - rB * 10;
    const int gy1 = y0 + rB - 1, gx1 = x0 + cB - 1;
    const bool v1ok = u1v && (gy1 >= 0) && (gy1 < W) && (gx1 >= 0) && (gx1 < W);
    const _Float16* ga1 = aIn + (size_t)(v1ok ? (gy1 * W + gx1) : 0) * 512
                          + ((sg1 < 4) ? sg1 * 8 : 256 + (sg1 - 4) * 8);
    _Float16* ls1 = Xs + px1 * 72 + ((sg1 & 4) ? 32 : 0)
                    + ((((sg1 & 3) + (px1 >> 3)) & 3) * 8);

    half8 st0 = v0ok ? *(const half8*)ga0 : z8;     // chunk 0 prefetch
    half8 st1 = v1ok ? *(const half8*)ga1 : z8;

    const size_t wsplit = (size_t)4096 * NC16;      // hi->lo element offset

    for (int cc = 0; cc < 8; cc++) {
        __syncthreads();
        *(half8*)ls0 = st0;
        if (u1v) *(half8*)ls1 = st1;
        __syncthreads();
        if (cc < 7) {   // prefetch next chunk's acts during this chunk's compute
            st0 = v0ok ? *(const half8*)(ga0 + (cc + 1) * 32) : z8;
            st1 = v1ok ? *(const half8*)(ga1 + (cc + 1) * 32) : z8;
        }

        if (active) {
#pragma unroll
            for (int tap = 0; tap < 9; tap++) {
                const int dy = tap / 3 - 1, dx = tap % 3 - 1;
                half8 ah[2], al[2];
#pragma unroll
                for (int mf = 0; mf < 2; mf++) {
                    int lpx = (2 * mf + (l15 >> 3) + 1 + dy) * 10 + (l15 & 7) + 1 + dx;
                    const _Float16* lp = Xs + lpx * 72 + (((quad + (lpx >> 3)) & 3) * 8);
                    ah[mf] = *(const half8*)lp;
                    al[mf] = *(const half8*)(lp + 32);
                }
                half8 bh[2], bl[2];
#pragma unroll
                for (int nf = 0; nf < 2; nf++) {
                    const _Float16* wb = wp +
                        ((((size_t)(tap * 2) * 8 + cc) * NC16 + c16b + nf) * 64 + lane) * 8;
                    bh[nf] = *(const half8*)wb;
                    bl[nf] = *(const half8*)(wb + wsplit);
                }
#pragma unroll
                for (int nf = 0; nf < 2; nf++) {
#pragma unroll
                    for (int mf = 0; mf < 2; mf++) {
                        acc[mf][nf] = __builtin_amdgcn_mfma_f32_16x16x32_f16(ah[mf], bh[nf], acc[mf][nf], 0, 0, 0);
                        acc[mf][nf] = __builtin_amdgcn_mfma_f32_16x16x32_f16(ah[mf], bl[nf], acc[mf][nf], 0, 0, 0);
                        acc[mf][nf] = __builtin_amdgcn_mfma_f32_16x16x32_f16(al[mf], bh[nf], acc[mf][nf], 0, 0, 0);
                    }
                }
            }
        }
    }

    if (!active) return;

    int coN[2];
    float bv[2];
#pragma unroll
    for (int nf = 0; nf < 2; nf++) {
        coN[nf] = coW + nf * 16 + l15;
        bv[nf] = (coN[nf] < Co) ? bias[coN[nf]] : 0.f;
    }

    // C layout: m = quad*4 + r -> y = y0 + 2*mf + (m>>3), x = x0 + (m&7)
    if (A.mode == 0) {
        _Float16* ao = (head ? A.aOut1 : A.aOut0) + (size_t)pxB[lv] * 512;
#pragma unroll
        for (int nf = 0; nf < 2; nf++) {
#pragma unroll
            for (int mf = 0; mf < 2; mf++) {
#pragma unroll
                for (int r = 0; r < 4; r++) {
                    int m = quad * 4 + r;
                    int yy = y0 + 2 * mf + (m >> 3);
                    int xx = x0 + (m & 7);
                    if (yy < W && xx < W) {
                        int px = yy * W + xx;
                        float v = fmaxf(acc[mf][nf][r] + bv[nf], 0.f);
                        _Float16 h = (_Float16)v;
                        _Float16 lo = (_Float16)(v - (float)h);
                        ao[(size_t)px * 512 + coN[nf]] = h;
                        ao[(size_t)px * 512 + 256 + coN[nf]] = lo;
                    }
                }
            }
        }
    } else {
        float* ho = (head ? A.hOut1 : A.hOut0) + (size_t)Co * pxB[lv];
#pragma unroll
        for (int nf = 0; nf < 2; nf++) {
            if (coN[nf] < Co) {
                float* col = ho + (size_t)coN[nf] * HW;
#pragma unroll
                for (int mf = 0; mf < 2; mf++) {
#pragma unroll
                    for (int r = 0; r < 4; r++) {
                        int m = quad * 4 + r;
                        int yy = y0 + 2 * mf + (m >> 3);
                        int xx = x0 + (m & 7);
                        if (yy < W && xx < W) col[yy * W + xx] = acc[mf][nf][r] + bv[nf];
                    }
                }
            }
        }
    }
}

// ---------------------------------------------------------------- cls reduce
// argmax MUST be in fp32 sigmoid domain: saturated classes tie at 1.0f and
// jnp.argmax picks the lowest tied class index (logit-domain argmax differs).
__global__ void cls_reduce_k(const float* __restrict__ ho,
                             u64* __restrict__ keys, int* __restrict__ cls_all)
{
    const int cumB[5] = {225, 282, 297, 301, 302};
    const int HWs[5]  = {6400, 1600, 400, 100, 25};
    const int pxB[5]  = {0, 6400, 8000, 8400, 8500};
    const int offs[5] = {0, 57600, 72000, 75600, 76500};
    int b = blockIdx.x;
    int lv = 0;
    while (b >= cumB[lv]) lv++;
    int local = (b - (lv ? cumB[lv - 1] : 0)) * 256 + threadIdx.x;
    const int HW = HWs[lv];
    if (local >= HW * 9) return;
    int a = local / HW, p = local - a * HW;
    const float* base = ho + (size_t)720 * pxB[lv] + (size_t)a * 80 * HW + p;
    float m = -1.f; int arg = 0;
    for (int c = 0; c < 80; c++) {
        float logit = base[(size_t)c * HW];
        float s = 1.0f / (1.0f + expf(-logit));
        if (s > m) { m = s; arg = c; }
    }
    float masked = (m > 0.05f) ? m : -1.0f;
    unsigned u = __float_as_uint(masked);
    unsigned su = (u & 0x80000000u) ? ~u : (u | 0x80000000u);
    int g = offs[lv] + p * 9 + a;
    keys[g] = ((u64)su << 32) | (u64)(0xFFFFFFFFu - (unsigned)g);
    cls_all[g] = arg;
}

// ---------------------------------------------------------------- decode
struct DecArgs { float aw[45]; float ah[45]; };

__global__ void decode_k(const float* __restrict__ ro, DecArgs D, float* __restrict__ boxes_all)
{
    const int cumB[5] = {225, 282, 297, 301, 302};
    const int HWs[5]  = {6400, 1600, 400, 100, 25};
    const int Wt[5]   = {80, 40, 20, 10, 5};
    const int pxB[5]  = {0, 6400, 8000, 8400, 8500};
    const int offs[5] = {0, 57600, 72000, 75600, 76500};
    const float strd[5] = {8.f, 16.f, 32.f, 64.f, 128.f};
    int b = blockIdx.x;
    int lv = 0;
    while (b >= cumB[lv]) lv++;
    int local = (b - (lv ? cumB[lv - 1] : 0)) * 256 + threadIdx.x;
    const int HW = HWs[lv], W = Wt[lv];
    if (local >= HW * 9) return;
    int a = local / HW, p = local - a * HW;
    int y = p / W, x = p - y * W;
    float cx0 = ((float)x + 0.5f) * strd[lv];
    float cy0 = ((float)y + 0.5f) * strd[lv];
    float aw = D.aw[lv * 9 + a], ahh = D.ah[lv * 9 + a];
    float ax1 = cx0 - aw * 0.5f, ax2 = cx0 + aw * 0.5f;
    float ay1 = cy0 - ahh * 0.5f, ay2 = cy0 + ahh * 0.5f;
    float w = ax2 - ax1, h = ay2 - ay1;
    float cx = ax1 + 0.5f * w, cy = ay1 + 0.5f * h;
    const float* base = ro + (size_t)36 * pxB[lv] + p;
    float l0 = base[(size_t)(a * 4 + 0) * HW];
    float l1 = base[(size_t)(a * 4 + 1) * HW];
    float l2 = base[(size_t)(a * 4 + 2) * HW];
    float l3 = base[(size_t)(a * 4 + 3) * HW];
    float dx = l0 * 0.1f, dy = l1 * 0.1f, dw = l2 * 0.2f, dh = l3 * 0.2f;
    float pcx = cx + dx * w, pcy = cy + dy * h;
    float pw = expf(dw) * w, ph = expf(dh) * h;
    float bx1 = fminf(fmaxf(pcx - 0.5f * pw, 0.f), 640.f);
    float by1 = fminf(fmaxf(pcy - 0.5f * ph, 0.f), 640.f);
    float bx2 = fminf(fmaxf(pcx + 0.5f * pw, 0.f), 640.f);
    float by2 = fminf(fmaxf(pcy + 0.5f * ph, 0.f), 640.f);
    int g = offs[lv] + p * 9 + a;
    boxes_all[g * 4 + 0] = bx1;
    boxes_all[g * 4 + 1] = by1;
    boxes_all[g * 4 + 2] = bx2;
    boxes_all[g * 4 + 3] = by2;
}

__global__ void pad_keys_k(u64* __restrict__ keys)
{
    int i = blockIdx.x * blockDim.x + threadIdx.x + NANCH;
    if (i < NPAD) keys[i] = 0ULL;
}

// ---------------------------------------------------------------- sort
__global__ __launch_bounds__(1024) void chunk_sort_desc_k(u64* __restrict__ keys)
{
    __shared__ u64 s[4096];
    const int base = blockIdx.x * 4096;
    for (int i = threadIdx.x; i < 4096; i += 1024) s[i] = keys[base + i];
    __syncthreads();
    for (int size = 2; size <= 4096; size <<= 1) {
        for (int stride = size >> 1; stride > 0; stride >>= 1) {
            for (int t = threadIdx.x; t < 2048; t += 1024) {
                int low = t & (stride - 1);
                int i = ((t - low) << 1) | low;
                int j = i + stride;
                bool desc = ((i & size) == 0);
                u64 a = s[i], b = s[j];
                if (desc ? (a < b) : (a > b)) { s[i] = b; s[j] = a; }
            }
            __syncthreads();
        }
    }
    for (int i = threadIdx.x; i < 4096; i += 1024) keys[base + i] = s[i];
}

__global__ __launch_bounds__(1024) void gather_top_k(const u64* __restrict__ keys,
                                                     u64* __restrict__ keys2)
{
    int i = blockIdx.x * 1024 + threadIdx.x;
    keys2[i] = keys[(i >> 10) * 4096 + (i & 1023)];
}

__global__ void bitonic_global_k(u64* __restrict__ keys, int size, int stride)
{
    int t = blockIdx.x * blockDim.x + threadIdx.x;
    int low = t & (stride - 1);
    int i = ((t - low) << 1) | low;
    int j = i + stride;
    bool desc = ((i & size) == 0);
    u64 a = keys[i], b = keys[j];
    if (desc ? (a < b) : (a > b)) { keys[i] = b; keys[j] = a; }
}

__global__ __launch_bounds__(1024) void bitonic_local_full_k(u64* __restrict__ keys)
{
    __shared__ u64 s[4096];
    const int base = blockIdx.x * 4096;
    for (int i = threadIdx.x; i < 4096; i += 1024) s[i] = keys[base + i];
    __syncthreads();
    for (int size = 2; size <= 4096; size <<= 1) {
        for (int stride = size >> 1; stride > 0; stride >>= 1) {
            for (int t = threadIdx.x; t < 2048; t += 1024) {
                int low = t & (stride - 1);
                int i = ((t - low) << 1) | low;
                int j = i + stride;
                bool desc = (((base + i) & size) == 0);
                u64 a = s[i], b = s[j];
                if (desc ? (a < b) : (a > b)) { s[i] = b; s[j] = a; }
            }
            __syncthreads();
        }
    }
    for (int i = threadIdx.x; i < 4096; i += 1024) keys[base + i] = s[i];
}

__global__ __launch_bounds__(1024) void bitonic_local_k(u64* __restrict__ keys, int size)
{
    __shared__ u64 s[4096];
    const int base = blockIdx.x * 4096;
    for (int i = threadIdx.x; i < 4096; i += 1024) s[i] = keys[base + i];
    __syncthreads();
    const bool desc = ((base & size) == 0);
    for (int stride = 2048; stride > 0; stride >>= 1) {
        for (int t = threadIdx.x; t < 2048; t += 1024) {
            int low = t & (stride - 1);
            int i = ((t - low) << 1) | low;
            int j = i + stride;
            u64 a = s[i], b = s[j];
            if (desc ? (a < b) : (a > b)) { s[i] = b; s[j] = a; }
        }
        __syncthreads();
    }
    for (int i = threadIdx.x; i < 4096; i += 1024) keys[base + i] = s[i];
}

// ---------------------------------------------------------------- NMS (mask-based)
__global__ void gather_cand_k(const u64* __restrict__ keys,
                              const float* __restrict__ boxes_all,
                              const int* __restrict__ cls_all,
                              float* __restrict__ cand)
{
    int i = blockIdx.x * 256 + threadIdx.x;
    if (i >= 1000) return;
    u64 k = keys[i];
    unsigned shi = (unsigned)(k >> 32);
    unsigned u = (shi & 0x80000000u) ? (shi ^ 0x80000000u) : ~shi;
    float val = __uint_as_float(u);
    int anchor = (int)(0xFFFFFFFFu - (unsigned)(k & 0xFFFFFFFFull));
    float x1 = boxes_all[anchor * 4 + 0];
    float y1 = boxes_all[anchor * 4 + 1];
    float x2 = boxes_all[anchor * 4 + 2];
    float y2 = boxes_all[anchor * 4 + 3];
    cand[i * 8 + 0] = x1;
    cand[i * 8 + 1] = y1;
    cand[i * 8 + 2] = x2;
    cand[i * 8 + 3] = y2;
    cand[i * 8 + 4] = fmaxf(x2 - x1, 0.f) * fmaxf(y2 - y1, 0.f);
    cand[i * 8 + 5] = val;
    cand[i * 8 + 6] = (float)cls_all[anchor];
    cand[i * 8 + 7] = (val > 0.0f) ? 1.f : 0.f;
}

__global__ __launch_bounds__(256) void iou_mask_k(const float* __restrict__ cand,
                                                  u64* __restrict__ mask)
{
    const int i = blockIdx.x;
    const float x1 = cand[i * 8 + 0], y1 = cand[i * 8 + 1];
    const float x2 = cand[i * 8 + 2], y2 = cand[i * 8 + 3];
    const float ar = cand[i * 8 + 4];
    const int tid = threadIdx.x;
    const int wave = tid >> 6, lane = tid & 63;
    for (int base = 0; base < 1024; base += 256) {
        int j = base + tid;
        bool sup = false;
        if (j < 1000 && j > i) {
            float jx1 = cand[j * 8 + 0], jy1 = cand[j * 8 + 1];
            float jx2 = cand[j * 8 + 2], jy2 = cand[j * 8 + 3];
            float jar = cand[j * 8 + 4];
            float xx1 = fmaxf(x1, jx1), yy1 = fmaxf(y1, jy1);
            float xx2 = fminf(x2, jx2), yy2 = fminf(y2, jy2);
            float inter = fmaxf(xx2 - xx1, 0.f) * fmaxf(yy2 - yy1, 0.f);
            float iou = inter / (ar + jar - inter + 1e-8f);
            sup = iou > 0.5f;
        }
        u64 ball = __ballot(sup);
        int word = (base >> 6) + wave;
        if (lane == 0) mask[(size_t)i * 16 + word] = ball;
    }
}

// Tiled register sweep: 16 tiles of 64. Mirrored suppressed word per tile
// (identical in all lanes) -> alive test is a LOCAL register op; the only
// cross-lane ops (shfl of row words, ballot, or-reduce) are independent of
// the serial chain. Exactly reproduces the reference greedy order.
__global__ __launch_bounds__(64) void nms_sweep_out_k(const float* __restrict__ cand,
                                                      const u64* __restrict__ M,
                                                      float* __restrict__ out)
{
    const int lane = threadIdx.x;

    u64 V[16];
#pragma unroll
    for (int t = 0; t < 16; t++) {
        int i = t * 64 + lane;
        bool v = (i < 1000) && (cand[i * 8 + 7] > 0.f);
        V[t] = __ballot(v);
    }

    u64 pend[16];
#pragma unroll
    for (int t = 0; t < 16; t++) pend[t] = 0;
    u64 aliveW[16];

    for (int T = 0; T < 16; T++) {
        u64 rw[16];
        int row = T * 64 + lane;
        for (int t = T; t < 16; t++)
            rw[t] = (row < 1000) ? M[(size_t)row * 16 + t] : 0ULL;

        u64 s = pend[T];
        u64 alive = 0;
        u64 myw = rw[T];
        const u64 VT = V[T];
#pragma unroll
        for (int i = 0; i < 64; i++) {
            u64 ri = __shfl(myw, i);
            bool a = ((VT >> i) & 1) && !((s >> i) & 1);
            if (a) { s |= ri; alive |= (1ULL << i); }
        }
        aliveW[T] = alive;

        for (int t = T + 1; t < 16; t++) {
            u64 c = ((alive >> lane) & 1) ? rw[t] : 0ULL;
#pragma unroll
            for (int d = 1; d < 64; d <<= 1) c |= __shfl_xor(c, d);
            pend[t] |= c;
        }
    }

    for (int i = lane; i < 1000; i += 64) {
        int kp = (int)((aliveW[i >> 6] >> (i & 63)) & 1);
        float m = kp ? 1.f : 0.f;
        out[i] = kp ? cand[i * 8 + 5] : 0.f;
        out[1000 + i] = cand[i * 8 + 6];
        out[2000 + i * 4 + 0] = m * cand[i * 8 + 0];
        out[2000 + i * 4 + 1] = m * cand[i * 8 + 1];
        out[2000 + i * 4 + 2] = m * cand[i * 8 + 2];
        out[2000 + i * 4 + 3] = m * cand[i * 8 + 3];
        out[6000 + i] = m;
    }
}

// ---------------------------------------------------------------- host
extern "C" void kernel_launch(void* const* d_in, const int* in_sizes, int n_in,
                              void* d_out, int out_size, void* d_ws, size_t ws_size,
                              hipStream_t stream)
{
    const float* feats[5];
    for (int i = 0; i < 5; i++) feats[i] = (const float*)d_in[i];
    const float* cls_w  = (const float*)d_in[5];
    const float* cls_b  = (const float*)d_in[6];
    const float* cls_hw = (const float*)d_in[7];
    const float* cls_hb = (const float*)d_in[8];
    const float* reg_w  = (const float*)d_in[9];
    const float* reg_b  = (const float*)d_in[10];
    const float* reg_hw = (const float*)d_in[11];
    const float* reg_hb = (const float*)d_in[12];
    float* out = (float*)d_out;

    // ---------- workspace layout
    char* ws = (char*)d_ws;
    size_t off = 0;
    auto alloc = [&](size_t sz) { size_t o = off; off += (sz + 255) & ~(size_t)255; return o; };

    size_t R0 = alloc((size_t)(HEADC_EL + HEADR_EL) * 4);   // headout / act2_feats overlay
    _Float16* act2_feats = (_Float16*)(ws + R0);
    float* headout_cls = (float*)(ws + R0);
    float* headout_reg = headout_cls + HEADC_EL;

    _Float16* a2_clsA = (_Float16*)(ws + alloc(ACT2_EL * 2));
    _Float16* a2_regA = (_Float16*)(ws + alloc(ACT2_EL * 2));
    _Float16* a2_clsB = (_Float16*)(ws + alloc(ACT2_EL * 2));
    _Float16* a2_regB = (_Float16*)(ws + alloc(ACT2_EL * 2));

    _Float16* wpc[4]; _Float16* wpr[4];
    for (int i = 0; i < 4; i++) wpc[i] = (_Float16*)(ws + alloc((size_t)TRUNK_WP_EL * 2));
    _Float16* wpch = (_Float16*)(ws + alloc((size_t)CLSH_WP_EL * 2));
    for (int i = 0; i < 4; i++) wpr[i] = (_Float16*)(ws + alloc((size_t)TRUNK_WP_EL * 2));
    _Float16* wprh = (_Float16*)(ws + alloc((size_t)REGH_WP_EL * 2));

    u64* keys  = (u64*)(ws + alloc((size_t)NPAD * 8));
    u64* keys2 = (u64*)(ws + alloc((size_t)NPAD2 * 8));
    float* boxes_all = (float*)(ws + alloc((size_t)NANCH * 16));
    int* cls_all = (int*)(ws + alloc((size_t)NANCH * 4));
    float* cand = (float*)(ws + alloc((size_t)1000 * 8 * 4));
    u64* mask = (u64*)(ws + alloc((size_t)1000 * 16 * 8));
    (void)ws_size;

    // ---------- weight prep
    PrepArgs P;
    long cum = 0;
    for (int e = 0; e < 10; e++) {
        const float* src; _Float16* dst; int Co, NC16;
        if (e < 4)      { src = cls_w + (size_t)e * 589824; dst = wpc[e]; Co = 256; NC16 = 16; }
        else if (e == 4){ src = cls_hw;                     dst = wpch;   Co = 720; NC16 = 48; }
        else if (e < 9) { src = reg_w + (size_t)(e - 5) * 589824; dst = wpr[e - 5]; Co = 256; NC16 = 16; }
        else            { src = reg_hw;                     dst = wprh;   Co = 36;  NC16 = 4; }
        P.src[e] = src; P.dst[e] = dst; P.Co[e] = Co; P.NC16[e] = NC16;
        P.base[e] = cum; cum += (long)9216 * NC16;
    }
    P.base[10] = cum;
    prep_k<<<(int)((cum + 255) / 256), 256, 0, stream>>>(P);

    pad_keys_k<<<(NPAD - NANCH + 255) / 256, 256, 0, stream>>>(keys);

    // ---------- feats repack
    RepArgs R;
    for (int lv = 0; lv < 5; lv++) R.src[lv] = feats[lv];
    R.dst = act2_feats;
    repack_k<<<135, 256, 0, stream>>>(R);

    // ---------- conv layers
    auto trunk = [&](const _Float16* i0, const _Float16* i1, _Float16* o0, _Float16* o1,
                     const _Float16* w0, const _Float16* w1, const float* b0, const float* b1) {
        C3Args C;
        C.aIn0 = i0; C.aIn1 = i1; C.aOut0 = o0; C.aOut1 = o1;
        C.hOut0 = nullptr; C.hOut1 = nullptr;
        C.wp0 = w0; C.wp1 = w1; C.bias0 = b0; C.bias1 = b1;
        C.CoPad0 = 256; C.CoPad1 = 256;
        C.Co0 = 256; C.Co1 = 256; C.mode = 0;
        conv3_k<<<8 * 2 * 69, 256, 0, stream>>>(C);
    };
    trunk(act2_feats, act2_feats, a2_clsA, a2_regA, wpc[0], wpr[0], cls_b + 0,   reg_b + 0);
    trunk(a2_clsA,    a2_regA,    a2_clsB, a2_regB, wpc[1], wpr[1], cls_b + 256, reg_b + 256);
    trunk(a2_clsB,    a2_regB,    a2_clsA, a2_regA, wpc[2], wpr[2], cls_b + 512, reg_b + 512);
    trunk(a2_clsA,    a2_regA,    a2_clsB, a2_regB, wpc[3], wpr[3], cls_b + 768, reg_b + 768);

    {   // head convs: combos 0..5 = cls 128-co groups, 6 = reg (2 active waves)
        C3Args C;
        C.aIn0 = a2_clsB; C.aIn1 = a2_regB;
        C.aOut0 = nullptr; C.aOut1 = nullptr;
        C.hOut0 = headout_cls; C.hOut1 = headout_reg;
        C.wp0 = wpch; C.wp1 = wprh; C.bias0 = cls_hb; C.bias1 = reg_hb;
        C.CoPad0 = 768; C.CoPad1 = 64;
        C.Co0 = 720; C.Co1 = 36; C.mode = 1;
        conv3_k<<<8 * 4 * 69, 256, 0, stream>>>(C);
    }

    // ---------- reduce + decode
    cls_reduce_k<<<302, 256, 0, stream>>>(headout_cls, keys, cls_all);

    DecArgs D;
    {
        const float sz[5] = {32.f, 64.f, 128.f, 256.f, 512.f};
        const float ratios[3] = {0.5f, 1.0f, 2.0f};
        const float scales[3] = {1.0f, 1.25992104989487316477f, 1.58740105196819947475f};
        for (int lv = 0; lv < 5; lv++)
            for (int r = 0; r < 3; r++)
                for (int s = 0; s < 3; s++) {
                    D.aw[lv * 9 + r * 3 + s] = sz[lv] * scales[s] / sqrtf(ratios[r]);
                    D.ah[lv * 9 + r * 3 + s] = sz[lv] * scales[s] * sqrtf(ratios[r]);
                }
    }
    decode_k<<<302, 256, 0, stream>>>(headout_reg, D, boxes_all);

    // ---------- top-K sort
    chunk_sort_desc_k<<<NPAD / 4096, 1024, 0, stream>>>(keys);
    gather_top_k<<<NPAD2 / 1024, 1024, 0, stream>>>(keys, keys2);
    bitonic_local_full_k<<<NPAD2 / 4096, 1024, 0, stream>>>(keys2);
    for (int size = 8192; size <= NPAD2; size <<= 1) {
        for (int stride = size >> 1; stride >= 4096; stride >>= 1)
            bitonic_global_k<<<NPAD2 / 2 / 1024, 1024, 0, stream>>>(keys2, size, stride);
        bitonic_local_k<<<NPAD2 / 4096, 1024, 0, stream>>>(keys2, size);
    }

    // ---------- NMS
    gather_cand_k<<<4, 256, 0, stream>>>(keys2, boxes_all, cls_all, cand);
    iou_mask_k<<<1000, 256, 0, stream>>>(cand, mask);
    nms_sweep_out_k<<<1, 64, 0, stream>>>(cand, mask, out);
}